// Round 2
// baseline (646.431 us; speedup 1.0000x reference)
//
#include <hip/hip_runtime.h>
#include <hip/hip_bf16.h>

#define HW 16384
#define W 128
#define C 128
#define HID 256

// ---------------- kernel 0: zero the stat accumulators ----------------
__global__ void zero_acc_kernel(float* acc) {
    acc[0] = 0.f;
    acc[1] = 0.f;
}

// ---------------- kernel 1: q/k/v 1x1 convs ----------------
// q -> q_t[pix][C]; k,v -> kv_t[pix][256] (k in [0,128), v in [128,256))
// grid 1024, block 256. 16 pixels per block.
__global__ void qkv_kernel(const float* __restrict__ q_in, const float* __restrict__ k_in,
                           const float* __restrict__ v_in,
                           const float* __restrict__ w_q, const float* __restrict__ w_k,
                           const float* __restrict__ w_v,
                           float* __restrict__ q_t, float* __restrict__ kv_t) {
    __shared__ float xs[3][C * 16];
    const int p0 = blockIdx.x * 16;
    const int t = threadIdx.x;

    #pragma unroll
    for (int it = 0; it < 8; ++it) {
        int e = t + 256 * it;          // e = c*16 + j
        int c = e >> 4, j = e & 15;
        xs[0][e] = q_in[c * HW + p0 + j];
        xs[1][e] = k_in[c * HW + p0 + j];
        xs[2][e] = v_in[c * HW + p0 + j];
    }
    __syncthreads();

    const int o = t & 127, half = t >> 7;
    const float* Ws[3] = {w_q, w_k, w_v};

    #pragma unroll
    for (int m = 0; m < 3; ++m) {
        float acc[8] = {0.f, 0.f, 0.f, 0.f, 0.f, 0.f, 0.f, 0.f};
        const float* Wr = Ws[m] + o * C;
        const float* xb = &xs[m][half * 8];
        for (int c = 0; c < C; ++c) {
            float w = Wr[c];
            const float* xr = xb + c * 16;
            #pragma unroll
            for (int i = 0; i < 8; ++i) acc[i] += w * xr[i];
        }
        #pragma unroll
        for (int i = 0; i < 8; ++i) {
            int p = p0 + half * 8 + i;
            if (m == 0)      q_t[p * C + o] = acc[i];
            else if (m == 1) kv_t[p * 256 + o] = acc[i];
            else             kv_t[p * 256 + 128 + o] = acc[i];
        }
    }
}

// ---------------- kernel 2: deformable sampling + attention ----------------
// grid 2048, block 256: 8 consecutive-x pixels per block, 32 threads per pixel,
// 4 channels per thread (float4 gathers). kv_t row = 1KB (k 512B | v 512B).
__global__ void attn_kernel(const float* __restrict__ q_t, const float* __restrict__ kv_t,
                            const float* __restrict__ deform, float* __restrict__ ao_t) {
    __shared__ int   s_off[8][25][4];
    __shared__ float s_w[8][25][4];

    // XCD-chunk swizzle: each XCD handles a contiguous band of 16 pixel rows
    int bid = blockIdx.x;
    int wg = (bid & 7) * 256 + (bid >> 3);
    const int y = wg >> 4;
    const int x0 = (wg & 15) * 8;
    const int t = threadIdx.x;
    const int pi = t >> 5;     // pixel within block
    const int g = t & 31;      // channel group (4 channels each)
    const int x = x0 + pi;
    const int pix = y * W + x;

    if (g < 25) {
        float dx = deform[pix];
        float dy = deform[HW + pix];
        int iy = g / 5, ix = g - iy * 5;
        float vx = (float)x + (float)(ix - 2) + dx;
        float vy = (float)y + (float)(iy - 2) + dy;
        float x0f = floorf(vx), y0f = floorf(vy);
        float fx = vx - x0f, fy = vy - y0f;
        float wx[2] = {1.f - fx, fx};
        float wy[2] = {1.f - fy, fy};
        #pragma unroll
        for (int cy = 0; cy < 2; ++cy) {
            #pragma unroll
            for (int cx = 0; cx < 2; ++cx) {
                float xf = x0f + (float)cx;
                float yf = y0f + (float)cy;
                bool valid = (xf >= 0.f) & (xf <= 127.f) & (yf >= 0.f) & (yf <= 127.f);
                int xi = min(max((int)xf, 0), 127);
                int yi = min(max((int)yf, 0), 127);
                s_off[pi][g][cy * 2 + cx] = (yi * W + xi) * 1024;   // byte offset of kv row
                s_w[pi][g][cy * 2 + cx] = valid ? wx[cx] * wy[cy] : 0.f;
            }
        }
    }
    __syncthreads();

    const char* kvb = (const char*)kv_t;
    const int go = g * 16;

    float4 q4 = *(const float4*)(q_t + (size_t)pix * C + 4 * g);
    q4.x *= 0.25f; q4.y *= 0.25f; q4.z *= 0.25f; q4.w *= 0.25f;   // 1/sqrt(16)

    // ---- phase A: scores ----
    float s[25];
    #pragma unroll
    for (int p = 0; p < 25; ++p) {
        int4   off = *(const int4*)&s_off[pi][p][0];
        float4 w   = *(const float4*)&s_w[pi][p][0];
        float4 k0 = *(const float4*)(kvb + off.x + go);
        float4 k1 = *(const float4*)(kvb + off.y + go);
        float4 k2 = *(const float4*)(kvb + off.z + go);
        float4 k3 = *(const float4*)(kvb + off.w + go);
        float4 ks;
        ks.x = w.x * k0.x + w.y * k1.x + w.z * k2.x + w.w * k3.x;
        ks.y = w.x * k0.y + w.y * k1.y + w.z * k2.y + w.w * k3.y;
        ks.z = w.x * k0.z + w.y * k1.z + w.z * k2.z + w.w * k3.z;
        ks.w = w.x * k0.w + w.y * k1.w + w.z * k2.w + w.w * k3.w;
        float sp = q4.x * ks.x + q4.y * ks.y + q4.z * ks.z + q4.w * ks.w;
        sp += __shfl_xor(sp, 1);
        sp += __shfl_xor(sp, 2);    // 4-thread group = one head (16 channels)
        s[p] = sp;
    }

    float m = s[0];
    #pragma unroll
    for (int p = 1; p < 25; ++p) m = fmaxf(m, s[p]);
    float sum = 0.f;
    #pragma unroll
    for (int p = 0; p < 25; ++p) {
        float e = __expf(s[p] - m);
        s[p] = e;
        sum += e;
    }
    float inv = 1.f / sum;

    // ---- phase B: PV ----
    float4 oc = {0.f, 0.f, 0.f, 0.f};
    #pragma unroll
    for (int p = 0; p < 25; ++p) {
        int4   off = *(const int4*)&s_off[pi][p][0];
        float4 w   = *(const float4*)&s_w[pi][p][0];
        float4 v0 = *(const float4*)(kvb + off.x + 512 + go);
        float4 v1 = *(const float4*)(kvb + off.y + 512 + go);
        float4 v2 = *(const float4*)(kvb + off.z + 512 + go);
        float4 v3 = *(const float4*)(kvb + off.w + 512 + go);
        float4 vs;
        vs.x = w.x * v0.x + w.y * v1.x + w.z * v2.x + w.w * v3.x;
        vs.y = w.x * v0.y + w.y * v1.y + w.z * v2.y + w.w * v3.y;
        vs.z = w.x * v0.z + w.y * v1.z + w.z * v2.z + w.w * v3.z;
        vs.w = w.x * v0.w + w.y * v1.w + w.z * v2.w + w.w * v3.w;
        oc.x += s[p] * vs.x;
        oc.y += s[p] * vs.y;
        oc.z += s[p] * vs.z;
        oc.w += s[p] * vs.w;
    }
    oc.x *= inv; oc.y *= inv; oc.z *= inv; oc.w *= inv;
    *(float4*)(ao_t + (size_t)pix * C + 4 * g) = oc;
}

// ---------------- kernel 3: fc + MLP + residual + stats ----------------
// grid 1024, block 256. 16 pixels per block. out2 goes straight into d_out [C][HW].
__global__ void mlp_kernel(const float* __restrict__ ao_t, const float* __restrict__ w_fc,
                           const float* __restrict__ w1, const float* __restrict__ b1,
                           const float* __restrict__ w2, const float* __restrict__ b2,
                           float* __restrict__ out2, float* __restrict__ accum) {
    __shared__ float xs[16 * C];    // ao[j][c]
    __shared__ float ys[16 * C];    // out1[j][o]
    __shared__ float hs[16 * HID];  // hid[j][h]
    __shared__ float rs[8];

    const int p0 = blockIdx.x * 16;
    const int t = threadIdx.x;

    #pragma unroll
    for (int it = 0; it < 8; ++it) {
        int e = t + 256 * it;
        xs[e] = ao_t[p0 * C + e];
    }
    __syncthreads();

    const int o = t & 127, half = t >> 7;
    float out1r[8];
    {
        float acc[8] = {0.f, 0.f, 0.f, 0.f, 0.f, 0.f, 0.f, 0.f};
        const float* Wr = w_fc + o * C;
        for (int c = 0; c < C; ++c) {
            float w = Wr[c];
            #pragma unroll
            for (int i = 0; i < 8; ++i) acc[i] += w * xs[(half * 8 + i) * C + c];
        }
        #pragma unroll
        for (int i = 0; i < 8; ++i) {
            out1r[i] = acc[i];
            ys[(half * 8 + i) * C + o] = acc[i];
        }
    }
    __syncthreads();
    {
        // hid: one hidden channel per thread (t in [0,256))
        float acc[16] = {0.f};
        const float* Wr = w1 + t * C;
        for (int c = 0; c < C; ++c) {
            float w = Wr[c];
            #pragma unroll
            for (int j = 0; j < 16; ++j) acc[j] += w * ys[j * C + c];
        }
        float bb = b1[t];
        #pragma unroll
        for (int j = 0; j < 16; ++j) {
            float v = acc[j] + bb;
            hs[j * HID + t] = (v >= 0.f) ? v : 0.2f * v;
        }
    }
    __syncthreads();
    float lsum = 0.f, lsq = 0.f;
    {
        float acc[8] = {0.f, 0.f, 0.f, 0.f, 0.f, 0.f, 0.f, 0.f};
        const float* Wr = w2 + o * HID;
        for (int h = 0; h < HID; ++h) {
            float w = Wr[h];
            #pragma unroll
            for (int i = 0; i < 8; ++i) acc[i] += w * hs[(half * 8 + i) * HID + h];
        }
        float bb = b2[o];
        #pragma unroll
        for (int i = 0; i < 8; ++i) {
            float v = out1r[i] + acc[i] + bb;
            out2[o * HW + p0 + half * 8 + i] = v;
            lsum += v;
            lsq += v * v;
        }
    }
    // block reduction for layernorm stats
    #pragma unroll
    for (int m = 1; m < 64; m <<= 1) {
        lsum += __shfl_xor(lsum, m);
        lsq  += __shfl_xor(lsq, m);
    }
    int wv = t >> 6, ln = t & 63;
    if (ln == 0) { rs[wv] = lsum; rs[4 + wv] = lsq; }
    __syncthreads();
    if (t == 0) {
        atomicAdd(&accum[0], rs[0] + rs[1] + rs[2] + rs[3]);
        atomicAdd(&accum[1], rs[4] + rs[5] + rs[6] + rs[7]);
    }
}

// ---------------- kernel 4: global layernorm (in place on d_out) ----------------
__global__ void norm_kernel(float* __restrict__ out2, const float* __restrict__ accum,
                            const float* __restrict__ gn_w, const float* __restrict__ gn_b) {
    const int gid = blockIdx.x * 256 + threadIdx.x;
    const float invN = 1.f / 2097152.f;
    float mean = accum[0] * invN;
    float var = accum[1] * invN - mean * mean;
    float rstd = rsqrtf(var + 1e-5f);
    int base = gid * 4;
    int o = base >> 14;    // / HW
    float g = gn_w[o] * rstd;
    float b = gn_b[o];
    float4 v = *(const float4*)(out2 + base);
    float4 r;
    r.x = (v.x - mean) * g + b;
    r.y = (v.y - mean) * g + b;
    r.z = (v.z - mean) * g + b;
    r.w = (v.w - mean) * g + b;
    *(float4*)(out2 + base) = r;
}

extern "C" void kernel_launch(void* const* d_in, const int* in_sizes, int n_in,
                              void* d_out, int out_size, void* d_ws, size_t ws_size,
                              hipStream_t stream) {
    const float* query  = (const float*)d_in[0];
    const float* key    = (const float*)d_in[1];
    const float* value  = (const float*)d_in[2];
    const float* deform = (const float*)d_in[3];
    const float* w_q    = (const float*)d_in[4];
    const float* w_k    = (const float*)d_in[5];
    const float* w_v    = (const float*)d_in[6];
    const float* w_fc   = (const float*)d_in[7];
    const float* mlp_w1 = (const float*)d_in[8];
    const float* mlp_b1 = (const float*)d_in[9];
    const float* mlp_w2 = (const float*)d_in[10];
    const float* mlp_b2 = (const float*)d_in[11];
    const float* gn_w   = (const float*)d_in[12];
    const float* gn_b   = (const float*)d_in[13];

    float* out = (float*)d_out;
    float* ws  = (float*)d_ws;

    const size_t T = (size_t)HW * C;   // 2,097,152 floats = 8 MB
    float* q_t  = ws;                  // 8 MB
    float* kv_t = ws + T;              // 16 MB (k|v interleaved per pixel)
    float* ao_t = ws + 3 * T;          // 8 MB
    float* acc  = ws + 4 * T;

    zero_acc_kernel<<<1, 1, 0, stream>>>(acc);
    qkv_kernel<<<1024, 256, 0, stream>>>(query, key, value, w_q, w_k, w_v, q_t, kv_t);
    attn_kernel<<<2048, 256, 0, stream>>>(q_t, kv_t, deform, ao_t);
    mlp_kernel<<<1024, 256, 0, stream>>>(ao_t, w_fc, mlp_w1, mlp_b1, mlp_w2, mlp_b2, out, acc);
    norm_kernel<<<2048, 256, 0, stream>>>(out, acc, gn_w, gn_b);
}

// Round 3
// 629.018 us; speedup vs baseline: 1.0277x; 1.0277x over previous
//
#include <hip/hip_runtime.h>
#include <hip/hip_bf16.h>

#define HW 16384
#define W 128
#define C 128
#define HID 256

// ---------------- kernel 0: zero the stat accumulators ----------------
__global__ void zero_acc_kernel(float* acc) {
    acc[0] = 0.f;
    acc[1] = 0.f;
}

// ---------------- kernel 1: q/k/v 1x1 convs ----------------
// q -> q_t[pix][C]; k,v -> kv_t[pix][256] (k in [0,128), v in [128,256))
// grid 1024, block 256. 16 pixels per block.
__global__ void qkv_kernel(const float* __restrict__ q_in, const float* __restrict__ k_in,
                           const float* __restrict__ v_in,
                           const float* __restrict__ w_q, const float* __restrict__ w_k,
                           const float* __restrict__ w_v,
                           float* __restrict__ q_t, float* __restrict__ kv_t) {
    __shared__ float xs[3][C * 16];
    const int p0 = blockIdx.x * 16;
    const int t = threadIdx.x;

    #pragma unroll
    for (int it = 0; it < 8; ++it) {
        int e = t + 256 * it;          // e = c*16 + j
        int c = e >> 4, j = e & 15;
        xs[0][e] = q_in[c * HW + p0 + j];
        xs[1][e] = k_in[c * HW + p0 + j];
        xs[2][e] = v_in[c * HW + p0 + j];
    }
    __syncthreads();

    const int o = t & 127, half = t >> 7;
    const float* Ws[3] = {w_q, w_k, w_v};

    #pragma unroll
    for (int m = 0; m < 3; ++m) {
        float acc[8] = {0.f, 0.f, 0.f, 0.f, 0.f, 0.f, 0.f, 0.f};
        const float* Wr = Ws[m] + o * C;
        const float* xb = &xs[m][half * 8];
        for (int c = 0; c < C; ++c) {
            float w = Wr[c];
            const float* xr = xb + c * 16;
            #pragma unroll
            for (int i = 0; i < 8; ++i) acc[i] += w * xr[i];
        }
        #pragma unroll
        for (int i = 0; i < 8; ++i) {
            int p = p0 + half * 8 + i;
            if (m == 0)      q_t[p * C + o] = acc[i];
            else if (m == 1) kv_t[p * 256 + o] = acc[i];
            else             kv_t[p * 256 + 128 + o] = acc[i];
        }
    }
}

// ---------------- kernel 2: deformable sampling + attention (online softmax) ----------------
// grid 2048, block 256: 8 consecutive-x pixels per block, 32 threads per pixel,
// 4 channels per thread (float4 gathers). kv_t row = 1KB (k 512B | v 512B).
// Online softmax: no per-tap arrays -> ~70 live VGPRs, no scratch.
__global__ __launch_bounds__(256, 4)
void attn_kernel(const float* __restrict__ q_t, const float* __restrict__ kv_t,
                 const float* __restrict__ deform, float* __restrict__ ao_t) {
    __shared__ int   s_off[8][25][4];
    __shared__ float s_w[8][25][4];

    // XCD-chunk swizzle: each XCD handles a contiguous band of 16 pixel rows
    int bid = blockIdx.x;
    int wg = (bid & 7) * 256 + (bid >> 3);
    const int y = wg >> 4;
    const int x0 = (wg & 15) * 8;
    const int t = threadIdx.x;
    const int pi = t >> 5;     // pixel within block
    const int g = t & 31;      // channel group (4 channels each)
    const int x = x0 + pi;
    const int pix = y * W + x;

    if (g < 25) {
        float dx = deform[pix];
        float dy = deform[HW + pix];
        int iy = g / 5, ix = g - iy * 5;
        float vx = (float)x + (float)(ix - 2) + dx;
        float vy = (float)y + (float)(iy - 2) + dy;
        float x0f = floorf(vx), y0f = floorf(vy);
        float fx = vx - x0f, fy = vy - y0f;
        float wx[2] = {1.f - fx, fx};
        float wy[2] = {1.f - fy, fy};
        #pragma unroll
        for (int cy = 0; cy < 2; ++cy) {
            #pragma unroll
            for (int cx = 0; cx < 2; ++cx) {
                float xf = x0f + (float)cx;
                float yf = y0f + (float)cy;
                bool valid = (xf >= 0.f) & (xf <= 127.f) & (yf >= 0.f) & (yf <= 127.f);
                int xi = min(max((int)xf, 0), 127);
                int yi = min(max((int)yf, 0), 127);
                s_off[pi][g][cy * 2 + cx] = (yi * W + xi) * 1024;   // byte offset of kv row
                s_w[pi][g][cy * 2 + cx] = valid ? wx[cx] * wy[cy] : 0.f;
            }
        }
    }
    __syncthreads();

    const char* kvb = (const char*)kv_t;
    const int go = g * 16;

    float4 q4 = *(const float4*)(q_t + (size_t)pix * C + 4 * g);
    q4.x *= 0.25f; q4.y *= 0.25f; q4.z *= 0.25f; q4.w *= 0.25f;   // 1/sqrt(16)

    float m = -1e30f;
    float sum = 0.f;
    float4 oc = {0.f, 0.f, 0.f, 0.f};

    #pragma unroll
    for (int p = 0; p < 25; ++p) {
        int4   off = *(const int4*)&s_off[pi][p][0];
        float4 w   = *(const float4*)&s_w[pi][p][0];
        float4 k0 = *(const float4*)(kvb + off.x + go);
        float4 k1 = *(const float4*)(kvb + off.y + go);
        float4 k2 = *(const float4*)(kvb + off.z + go);
        float4 k3 = *(const float4*)(kvb + off.w + go);
        float4 v0 = *(const float4*)(kvb + off.x + 512 + go);
        float4 v1 = *(const float4*)(kvb + off.y + 512 + go);
        float4 v2 = *(const float4*)(kvb + off.z + 512 + go);
        float4 v3 = *(const float4*)(kvb + off.w + 512 + go);

        float4 ks;
        ks.x = w.x * k0.x + w.y * k1.x + w.z * k2.x + w.w * k3.x;
        ks.y = w.x * k0.y + w.y * k1.y + w.z * k2.y + w.w * k3.y;
        ks.z = w.x * k0.z + w.y * k1.z + w.z * k2.z + w.w * k3.z;
        ks.w = w.x * k0.w + w.y * k1.w + w.z * k2.w + w.w * k3.w;
        float sp = q4.x * ks.x + q4.y * ks.y + q4.z * ks.z + q4.w * ks.w;
        sp += __shfl_xor(sp, 1);
        sp += __shfl_xor(sp, 2);    // 4-thread group = one head (16 channels)

        float4 vs;
        vs.x = w.x * v0.x + w.y * v1.x + w.z * v2.x + w.w * v3.x;
        vs.y = w.x * v0.y + w.y * v1.y + w.z * v2.y + w.w * v3.y;
        vs.z = w.x * v0.z + w.y * v1.z + w.z * v2.z + w.w * v3.z;
        vs.w = w.x * v0.w + w.y * v1.w + w.z * v2.w + w.w * v3.w;

        float mn   = fmaxf(m, sp);
        float corr = __expf(m - mn);
        float e    = __expf(sp - mn);
        sum  = sum * corr + e;
        oc.x = oc.x * corr + e * vs.x;
        oc.y = oc.y * corr + e * vs.y;
        oc.z = oc.z * corr + e * vs.z;
        oc.w = oc.w * corr + e * vs.w;
        m = mn;
    }

    float inv = 1.f / sum;
    oc.x *= inv; oc.y *= inv; oc.z *= inv; oc.w *= inv;
    *(float4*)(ao_t + (size_t)pix * C + 4 * g) = oc;
}

// ---------------- kernel 3: fc + MLP + residual + stats ----------------
// grid 1024, block 256. 16 pixels per block. out2 goes straight into d_out [C][HW].
__global__ void mlp_kernel(const float* __restrict__ ao_t, const float* __restrict__ w_fc,
                           const float* __restrict__ w1, const float* __restrict__ b1,
                           const float* __restrict__ w2, const float* __restrict__ b2,
                           float* __restrict__ out2, float* __restrict__ accum) {
    __shared__ float xs[16 * C];    // ao[j][c]
    __shared__ float ys[16 * C];    // out1[j][o]
    __shared__ float hs[16 * HID];  // hid[j][h]
    __shared__ float rs[8];

    const int p0 = blockIdx.x * 16;
    const int t = threadIdx.x;

    #pragma unroll
    for (int it = 0; it < 8; ++it) {
        int e = t + 256 * it;
        xs[e] = ao_t[p0 * C + e];
    }
    __syncthreads();

    const int o = t & 127, half = t >> 7;
    float out1r[8];
    {
        float acc[8] = {0.f, 0.f, 0.f, 0.f, 0.f, 0.f, 0.f, 0.f};
        const float* Wr = w_fc + o * C;
        for (int c = 0; c < C; ++c) {
            float w = Wr[c];
            #pragma unroll
            for (int i = 0; i < 8; ++i) acc[i] += w * xs[(half * 8 + i) * C + c];
        }
        #pragma unroll
        for (int i = 0; i < 8; ++i) {
            out1r[i] = acc[i];
            ys[(half * 8 + i) * C + o] = acc[i];
        }
    }
    __syncthreads();
    {
        // hid: one hidden channel per thread (t in [0,256))
        float acc[16] = {0.f};
        const float* Wr = w1 + t * C;
        for (int c = 0; c < C; ++c) {
            float w = Wr[c];
            #pragma unroll
            for (int j = 0; j < 16; ++j) acc[j] += w * ys[j * C + c];
        }
        float bb = b1[t];
        #pragma unroll
        for (int j = 0; j < 16; ++j) {
            float v = acc[j] + bb;
            hs[j * HID + t] = (v >= 0.f) ? v : 0.2f * v;
        }
    }
    __syncthreads();
    float lsum = 0.f, lsq = 0.f;
    {
        float acc[8] = {0.f, 0.f, 0.f, 0.f, 0.f, 0.f, 0.f, 0.f};
        const float* Wr = w2 + o * HID;
        for (int h = 0; h < HID; ++h) {
            float w = Wr[h];
            #pragma unroll
            for (int i = 0; i < 8; ++i) acc[i] += w * hs[(half * 8 + i) * HID + h];
        }
        float bb = b2[o];
        #pragma unroll
        for (int i = 0; i < 8; ++i) {
            float v = out1r[i] + acc[i] + bb;
            out2[o * HW + p0 + half * 8 + i] = v;
            lsum += v;
            lsq += v * v;
        }
    }
    // block reduction for layernorm stats
    #pragma unroll
    for (int m = 1; m < 64; m <<= 1) {
        lsum += __shfl_xor(lsum, m);
        lsq  += __shfl_xor(lsq, m);
    }
    int wv = t >> 6, ln = t & 63;
    if (ln == 0) { rs[wv] = lsum; rs[4 + wv] = lsq; }
    __syncthreads();
    if (t == 0) {
        atomicAdd(&accum[0], rs[0] + rs[1] + rs[2] + rs[3]);
        atomicAdd(&accum[1], rs[4] + rs[5] + rs[6] + rs[7]);
    }
}

// ---------------- kernel 4: global layernorm (in place on d_out) ----------------
__global__ void norm_kernel(float* __restrict__ out2, const float* __restrict__ accum,
                            const float* __restrict__ gn_w, const float* __restrict__ gn_b) {
    const int gid = blockIdx.x * 256 + threadIdx.x;
    const float invN = 1.f / 2097152.f;
    float mean = accum[0] * invN;
    float var = accum[1] * invN - mean * mean;
    float rstd = rsqrtf(var + 1e-5f);
    int base = gid * 4;
    int o = base >> 14;    // / HW
    float g = gn_w[o] * rstd;
    float b = gn_b[o];
    float4 v = *(const float4*)(out2 + base);
    float4 r;
    r.x = (v.x - mean) * g + b;
    r.y = (v.y - mean) * g + b;
    r.z = (v.z - mean) * g + b;
    r.w = (v.w - mean) * g + b;
    *(float4*)(out2 + base) = r;
}

extern "C" void kernel_launch(void* const* d_in, const int* in_sizes, int n_in,
                              void* d_out, int out_size, void* d_ws, size_t ws_size,
                              hipStream_t stream) {
    const float* query  = (const float*)d_in[0];
    const float* key    = (const float*)d_in[1];
    const float* value  = (const float*)d_in[2];
    const float* deform = (const float*)d_in[3];
    const float* w_q    = (const float*)d_in[4];
    const float* w_k    = (const float*)d_in[5];
    const float* w_v    = (const float*)d_in[6];
    const float* w_fc   = (const float*)d_in[7];
    const float* mlp_w1 = (const float*)d_in[8];
    const float* mlp_b1 = (const float*)d_in[9];
    const float* mlp_w2 = (const float*)d_in[10];
    const float* mlp_b2 = (const float*)d_in[11];
    const float* gn_w   = (const float*)d_in[12];
    const float* gn_b   = (const float*)d_in[13];

    float* out = (float*)d_out;
    float* ws  = (float*)d_ws;

    const size_t T = (size_t)HW * C;   // 2,097,152 floats = 8 MB
    float* q_t  = ws;                  // 8 MB
    float* kv_t = ws + T;              // 16 MB (k|v interleaved per pixel)
    float* ao_t = ws + 3 * T;          // 8 MB
    float* acc  = ws + 4 * T;

    zero_acc_kernel<<<1, 1, 0, stream>>>(acc);
    qkv_kernel<<<1024, 256, 0, stream>>>(query, key, value, w_q, w_k, w_v, q_t, kv_t);
    attn_kernel<<<2048, 256, 0, stream>>>(q_t, kv_t, deform, ao_t);
    mlp_kernel<<<1024, 256, 0, stream>>>(ao_t, w_fc, mlp_w1, mlp_b1, mlp_w2, mlp_b2, out, acc);
    norm_kernel<<<2048, 256, 0, stream>>>(out, acc, gn_w, gn_b);
}